// Round 5
// baseline (2458.361 us; speedup 1.0000x reference)
//
#include <hip/hip_runtime.h>

typedef __bf16 bf16_t;
typedef __bf16 bf16x8 __attribute__((ext_vector_type(8)));
typedef __bf16 bf16x4 __attribute__((ext_vector_type(4)));
typedef __bf16 bf16x2 __attribute__((ext_vector_type(2)));
typedef float f32x4 __attribute__((ext_vector_type(4)));

#define SCALE 0.17677669529663687f

__device__ __forceinline__ f32x4 mfma16(bf16x8 a, bf16x8 b, f32x4 c) {
  return __builtin_amdgcn_mfma_f32_16x16x32_bf16(a, b, c, 0, 0, 0);
}

// XOR-swizzled LDS byte offset: 16B-granule index XORed with (row&7).
__device__ __forceinline__ int swz(int row, int colByte, int strideB) {
  return row * strideB + ((((colByte >> 4) ^ (row & 7)) << 4) | (colByte & 15));
}

// Barrier that does NOT drain vmcnt: LDS-producer-safe (lgkmcnt(0)), keeps
// global prefetch loads in flight across phases (the whole point of r5).
__device__ __forceinline__ void barrier_nd() {
  asm volatile("s_waitcnt lgkmcnt(0)" ::: "memory");
  __builtin_amdgcn_s_barrier();
  asm volatile("" ::: "memory");
}

union CvtU { bf16x2 h; unsigned int u; };
union PaU { unsigned int u[4]; bf16x8 v; };

// ws: bf16 weights [0,147456) elems (294912 B), then bias f32 [6][64][64] (98304 B)
__global__ void prep(const float* __restrict__ qw, const float* __restrict__ kvw,
                     const float* __restrict__ pw, const float* __restrict__ table,
                     bf16_t* __restrict__ wsb, float* __restrict__ biasws) {
  int bid = blockIdx.x;
  if (bid < 144) {
    int i = bid * 256 + threadIdx.x;
#pragma unroll
    for (int j = 0; j < 4; ++j) {
      int e = i * 4 + j;
      float v;
      if (e < 36864) v = qw[e];
      else if (e < 110592) v = kvw[e - 36864];
      else v = pw[e - 110592];
      wsb[e] = (bf16_t)v;
    }
  } else {
    int e = (bid - 144) * 256 + threadIdx.x;  // [0, 24576)
    int h = e >> 12, rc = e & 4095, r = rc >> 6, c = rc & 63;
    int rel = ((r >> 3) - (c >> 3) + 7) * 15 + ((r & 7) - (c & 7) + 7);
    biasws[e] = table[rel * 6 + h];
  }
}

template <bool WS>
__device__ __forceinline__ bf16x8 ldw(const bf16_t* __restrict__ wb,
                                      const float* __restrict__ wf, int off) {
  if constexpr (WS) {
    return *(const bf16x8*)(wb + off);
  } else {
    const float4* p = (const float4*)(wf + off);
    float4 a = p[0], c = p[1];
    bf16x8 r;
    r[0] = (bf16_t)a.x; r[1] = (bf16_t)a.y; r[2] = (bf16_t)a.z; r[3] = (bf16_t)a.w;
    r[4] = (bf16_t)c.x; r[5] = (bf16_t)c.y; r[6] = (bf16_t)c.z; r[7] = (bf16_t)c.w;
    return r;
  }
}

// Persistent: 512 blocks x 16 windows, 512 threads = 8 waves, 72 KB LDS -> 2 blocks/CU.
//   R0 @     0 : x2 staged -> Q           (stride 384, swizzled)
//   R1 @ 24576 : K -> att-out (per-head)  (stride 384, swizzled)
//   R2 @ 49152 : V^T [192][64]            (stride 128, swizzled)
// Cross-window pipeline: x1(j) issued pre-phase-A, consumed phase-B;
// x2(j+1) issued post-phase-B-MFMA, consumed next loop top. No accumulator
// and no prefetch register block exceeds ~115 VGPR at any point.
template <bool WS>
__global__ __attribute__((amdgpu_flat_work_group_size(512, 512),
                          amdgpu_waves_per_eu(4, 4)))
void wca_main(
    const float* __restrict__ x1, const float* __restrict__ x2,
    const float* __restrict__ mask,
    const float* __restrict__ qw_f, const float* __restrict__ qb,
    const float* __restrict__ kvw_f, const float* __restrict__ kvb,
    const float* __restrict__ pw_f, const float* __restrict__ pb,
    const float* __restrict__ table,
    const bf16_t* __restrict__ wsb, const float* __restrict__ biasws,
    float* __restrict__ out) {
  extern __shared__ char smem[];
  char* R0 = smem;
  char* R1 = smem + 24576;
  char* R2 = smem + 49152;

  const int t = threadIdx.x;
  const int w = t >> 6, l = t & 63, lo = l & 15, hi = l >> 4;
  const int bid = blockIdx.x;
  const int rtB = w & 3, cgB = w >> 2;  // phase-B / out-proj wave mapping

  const bf16_t* q_wb = wsb;
  const bf16_t* kv_wb = wsb + 36864;
  const bf16_t* p_wb = wsb + 110592;

  // prologue: prefetch x2 for window bid
  float4 c2[6];
  {
    const float4* s2 = (const float4*)(x2 + (size_t)bid * 12288);
#pragma unroll
    for (int it = 0; it < 3; ++it) {
      int idx = it * 512 + t;
      c2[2 * it] = s2[2 * idx];
      c2[2 * it + 1] = s2[2 * idx + 1];
    }
  }

#pragma unroll 1
  for (int j = 0; j < 16; ++j) {
    const int win = bid + 512 * j;

    // ---------- (1) write staged x2 -> R0 (f32 -> bf16, swizzled) ----------
#pragma unroll
    for (int it = 0; it < 3; ++it) {
      int idx = it * 512 + t;
      int n = idx / 24, g = idx - n * 24;
      float4 a = c2[2 * it], c = c2[2 * it + 1];
      bf16x8 v;
      v[0] = (bf16_t)a.x; v[1] = (bf16_t)a.y; v[2] = (bf16_t)a.z; v[3] = (bf16_t)a.w;
      v[4] = (bf16_t)c.x; v[5] = (bf16_t)c.y; v[6] = (bf16_t)c.z; v[7] = (bf16_t)c.w;
      *(bf16x8*)(R0 + swz(n, g * 16, 384)) = v;
    }
    // ---------- (2) issue x1 loads for this window (consumed in phase B) ----------
    float4 xa[6], xb[6];
    {
      const float4* x1p = (const float4*)(x1 + (size_t)win * 12288 + (rtB * 16 + lo) * 192);
#pragma unroll
      for (int kk = 0; kk < 6; ++kk) {
        xa[kk] = x1p[kk * 8 + hi * 2];
        xb[kk] = x1p[kk * 8 + hi * 2 + 1];
      }
    }
    barrier_nd();

    // ---------- (3) phase A: KV proj, all 8 waves, two row-halves ----------
    // wave w: K cols w*48.. (w<4) or V cols (w-4)*48.. (w>=4)
#pragma unroll
    for (int h2 = 0; h2 < 2; ++h2) {
      f32x4 acc[2][3];
#pragma unroll
      for (int rt2 = 0; rt2 < 2; ++rt2)
#pragma unroll
        for (int ct = 0; ct < 3; ++ct) { f32x4 z = {0.f, 0.f, 0.f, 0.f}; acc[rt2][ct] = z; }
#pragma unroll
      for (int kk = 0; kk < 6; ++kk) {
        bf16x8 a[2];
#pragma unroll
        for (int rt2 = 0; rt2 < 2; ++rt2)
          a[rt2] = *(const bf16x8*)(R0 + swz((h2 * 2 + rt2) * 16 + lo, (kk * 4 + hi) * 16, 384));
        bf16x8 bw[3];
#pragma unroll
        for (int ct = 0; ct < 3; ++ct) {
          int row = w * 48 + ct * 16 + lo;
          bw[ct] = ldw<WS>(kv_wb, kvw_f, row * 192 + kk * 32 + hi * 8);
        }
#pragma unroll
        for (int rt2 = 0; rt2 < 2; ++rt2)
#pragma unroll
          for (int ct = 0; ct < 3; ++ct)
            acc[rt2][ct] = mfma16(a[rt2], bw[ct], acc[rt2][ct]);
      }
      if (w < 4) {
#pragma unroll
        for (int ct = 0; ct < 3; ++ct) {
          int och = w * 48 + ct * 16 + lo;
          float bv = kvb[och];
#pragma unroll
          for (int rt2 = 0; rt2 < 2; ++rt2)
#pragma unroll
            for (int i = 0; i < 4; ++i)
              *(bf16_t*)(R1 + swz((h2 * 2 + rt2) * 16 + hi * 4 + i, och * 2, 384)) =
                  (bf16_t)(acc[rt2][ct][i] + bv);
        }
      } else {
#pragma unroll
        for (int ct = 0; ct < 3; ++ct) {
          int och = (w - 4) * 48 + ct * 16 + lo;
          float bv = kvb[192 + och];
#pragma unroll
          for (int rt2 = 0; rt2 < 2; ++rt2) {
            int n0 = (h2 * 2 + rt2) * 16 + hi * 4;
            bf16x4 pk;
#pragma unroll
            for (int i = 0; i < 4; ++i) pk[i] = (bf16_t)(acc[rt2][ct][i] + bv);
            *(bf16x4*)(R2 + swz(och, n0 * 2, 128)) = pk;
          }
        }
      }
    }
    barrier_nd();  // x2 reads done; K, V^T ready

    // ---------- (4) phase B: Q proj from prefetched x1 regs ----------
    {
      f32x4 acc[6];
#pragma unroll
      for (int ct = 0; ct < 6; ++ct) { f32x4 z = {0.f, 0.f, 0.f, 0.f}; acc[ct] = z; }
#pragma unroll
      for (int kk = 0; kk < 6; ++kk) {
        bf16x8 a;
        a[0] = (bf16_t)xa[kk].x; a[1] = (bf16_t)xa[kk].y;
        a[2] = (bf16_t)xa[kk].z; a[3] = (bf16_t)xa[kk].w;
        a[4] = (bf16_t)xb[kk].x; a[5] = (bf16_t)xb[kk].y;
        a[6] = (bf16_t)xb[kk].z; a[7] = (bf16_t)xb[kk].w;
        bf16x8 bw[6];
#pragma unroll
        for (int ct = 0; ct < 6; ++ct) {
          int col = cgB * 96 + ct * 16 + lo;
          bw[ct] = ldw<WS>(q_wb, qw_f, col * 192 + kk * 32 + hi * 8);
        }
#pragma unroll
        for (int ct = 0; ct < 6; ++ct) acc[ct] = mfma16(a, bw[ct], acc[ct]);
      }
      // issue x2 prefetch for next window (hidden under attention + out proj)
      if (j < 15) {
        const float4* s2 = (const float4*)(x2 + (size_t)(win + 512) * 12288);
#pragma unroll
        for (int it = 0; it < 3; ++it) {
          int idx = it * 512 + t;
          c2[2 * it] = s2[2 * idx];
          c2[2 * it + 1] = s2[2 * idx + 1];
        }
      }
#pragma unroll
      for (int ct = 0; ct < 6; ++ct) {
        int col = cgB * 96 + ct * 16 + lo;
        float bv = qb[col];
#pragma unroll
        for (int i = 0; i < 4; ++i)
          *(bf16_t*)(R0 + swz(rtB * 16 + hi * 4 + i, col * 2, 384)) =
              (bf16_t)((acc[ct][i] + bv) * SCALE);
      }
    }
    barrier_nd();  // Q ready

    // ---------- (5) attention: wave = (rowtile w>>1, head-half w&1) ----------
    {
      const int rt3 = w >> 1, hh = w & 1, rbase = rt3 * 16;
      const int r = rbase + lo;  // this lane's softmax row (q)
      const float* maskp = mask + (size_t)(win & 1023) * 4096 + r * 64;
      f32x4 mk[4];
      int relidx[4][4];
#pragma unroll
      for (int ct = 0; ct < 4; ++ct) {
        mk[ct] = *(const f32x4*)(maskp + ct * 16 + hi * 4);
        if (!WS) {
#pragma unroll
          for (int i = 0; i < 4; ++i) {
            int c = ct * 16 + hi * 4 + i;
            relidx[ct][i] = (((r >> 3) - (c >> 3) + 7) * 15 + ((r & 7) - (c & 7) + 7)) * 6;
          }
        }
      }
#pragma unroll
      for (int hq = 0; hq < 3; ++hq) {
        const int h = hh * 3 + hq;
        bf16x8 qa = *(const bf16x8*)(R0 + swz(r, h * 64 + hi * 16, 384));
        f32x4 s[4];
#pragma unroll
        for (int ct = 0; ct < 4; ++ct) {
          f32x4 ci;
          if (WS) {
            ci = *(const f32x4*)(biasws + h * 4096 + r * 64 + ct * 16 + hi * 4);
          } else {
#pragma unroll
            for (int i = 0; i < 4; ++i) ci[i] = table[relidx[ct][i] + h];
          }
          ci += mk[ct];
          bf16x8 ka = *(const bf16x8*)(R1 + swz(ct * 16 + lo, h * 64 + hi * 16, 384));
          s[ct] = mfma16(ka, qa, ci);  // S^T: lane holds S[r][c=ct*16+hi*4+i]
        }
        float mx = -1e30f;
#pragma unroll
        for (int ct = 0; ct < 4; ++ct)
#pragma unroll
          for (int i = 0; i < 4; ++i) mx = fmaxf(mx, s[ct][i]);
        mx = fmaxf(mx, __shfl_xor(mx, 16));
        mx = fmaxf(mx, __shfl_xor(mx, 32));
        float sum = 0.f;
#pragma unroll
        for (int ct = 0; ct < 4; ++ct)
#pragma unroll
          for (int i = 0; i < 4; ++i) {
            float p = __expf(s[ct][i] - mx);
            s[ct][i] = p;
            sum += p;
          }
        sum += __shfl_xor(sum, 16);
        sum += __shfl_xor(sum, 32);
        float rinv = 1.0f / sum;
        unsigned int word[4][2];
#pragma unroll
        for (int ct = 0; ct < 4; ++ct)
#pragma unroll
          for (int i2 = 0; i2 < 2; ++i2) {
            CvtU cu;
            cu.h[0] = (bf16_t)(s[ct][2 * i2] * rinv);
            cu.h[1] = (bf16_t)(s[ct][2 * i2 + 1] * rinv);
            word[ct][i2] = cu.u;
          }
        // PV: build A-frag P[r'=rbase+lo][k-run] via shfl word-pulls
        f32x4 o0 = {0.f, 0.f, 0.f, 0.f}, o1 = {0.f, 0.f, 0.f, 0.f};
#pragma unroll
        for (int k2 = 0; k2 < 2; ++k2) {
          PaU pa;
#pragma unroll
          for (int j2 = 0; j2 < 4; ++j2) {
            int src = lo + ((hi & 1) << 5) + ((j2 >> 1) << 4);
            unsigned int wa = (unsigned int)__shfl((int)word[2 * k2][j2 & 1], src);
            unsigned int wb = (unsigned int)__shfl((int)word[2 * k2 + 1][j2 & 1], src);
            pa.u[j2] = (hi & 2) ? wb : wa;
          }
          bf16x8 v0 = *(const bf16x8*)(R2 + swz(h * 32 + lo, k2 * 64 + hi * 16, 128));
          bf16x8 v1 = *(const bf16x8*)(R2 + swz(h * 32 + 16 + lo, k2 * 64 + hi * 16, 128));
          o0 = mfma16(pa.v, v0, o0);
          o1 = mfma16(pa.v, v1, o1);
        }
        barrier_nd();  // all QK reads of head hq's K cols complete
#pragma unroll
        for (int i = 0; i < 4; ++i) {
          int rr = rbase + hi * 4 + i;
          *(bf16_t*)(R1 + swz(rr, h * 64 + lo * 2, 384)) = (bf16_t)o0[i];
          *(bf16_t*)(R1 + swz(rr, h * 64 + 32 + lo * 2, 384)) = (bf16_t)o1[i];
        }
      }
    }
    barrier_nd();  // att-out fully in R1

    // ---------- (6) out proj: wave = (rtB, cgB) ----------
    {
      f32x4 acc[6];
#pragma unroll
      for (int ct = 0; ct < 6; ++ct) { f32x4 z = {0.f, 0.f, 0.f, 0.f}; acc[ct] = z; }
#pragma unroll
      for (int kk = 0; kk < 6; ++kk) {
        bf16x8 a = *(const bf16x8*)(R1 + swz(rtB * 16 + lo, (kk * 4 + hi) * 16, 384));
        bf16x8 bw[6];
#pragma unroll
        for (int ct = 0; ct < 6; ++ct) {
          int col = cgB * 96 + ct * 16 + lo;
          bw[ct] = ldw<WS>(p_wb, pw_f, col * 192 + kk * 32 + hi * 8);
        }
#pragma unroll
        for (int ct = 0; ct < 6; ++ct) acc[ct] = mfma16(a, bw[ct], acc[ct]);
      }
      float* outp = out + (size_t)win * 12288;
#pragma unroll
      for (int ct = 0; ct < 6; ++ct) {
        int col = cgB * 96 + ct * 16 + lo;
        float bv = pb[col];
#pragma unroll
        for (int i = 0; i < 4; ++i)
          outp[(rtB * 16 + hi * 4 + i) * 192 + col] = acc[ct][i] + bv;
      }
    }
    // loop top re-writes R0 (x2 of j+1): its last readers (attention Q reads)
    // are ordered by the post-attention barrier; phase-A' reads are ordered by
    // the barrier after the stage write.
  }
}

extern "C" void kernel_launch(void* const* d_in, const int* in_sizes, int n_in,
                              void* d_out, int out_size, void* d_ws, size_t ws_size,
                              hipStream_t stream) {
  const float* x1 = (const float*)d_in[0];
  const float* x2 = (const float*)d_in[1];
  const float* mask = (const float*)d_in[2];
  const float* qw = (const float*)d_in[3];
  const float* qb = (const float*)d_in[4];
  const float* kvw = (const float*)d_in[5];
  const float* kvb = (const float*)d_in[6];
  const float* pw = (const float*)d_in[7];
  const float* pb = (const float*)d_in[8];
  const float* table = (const float*)d_in[9];
  float* out = (float*)d_out;
  bf16_t* wsb = (bf16_t*)d_ws;
  float* biasws = (float*)((char*)d_ws + 294912);
  const int LDS_BYTES = 73728;
  if (ws_size >= 393216) {
    prep<<<240, 256, 0, stream>>>(qw, kvw, pw, table, wsb, biasws);
    wca_main<true><<<512, 512, LDS_BYTES, stream>>>(x1, x2, mask, qw, qb, kvw, kvb,
                                                    pw, pb, table, wsb, biasws, out);
  } else {
    wca_main<false><<<512, 512, LDS_BYTES, stream>>>(x1, x2, mask, qw, qb, kvw, kvb,
                                                     pw, pb, table, wsb, biasws, out);
  }
}

// Round 6
// 995.067 us; speedup vs baseline: 2.4705x; 2.4705x over previous
//
#include <hip/hip_runtime.h>

typedef __bf16 bf16_t;
typedef __bf16 bf16x8 __attribute__((ext_vector_type(8)));
typedef __bf16 bf16x4 __attribute__((ext_vector_type(4)));
typedef __bf16 bf16x2 __attribute__((ext_vector_type(2)));
typedef float f32x4 __attribute__((ext_vector_type(4)));

#define SCALE 0.17677669529663687f

__device__ __forceinline__ f32x4 mfma16(bf16x8 a, bf16x8 b, f32x4 c) {
  return __builtin_amdgcn_mfma_f32_16x16x32_bf16(a, b, c, 0, 0, 0);
}

// XOR-swizzled LDS byte offset: 16B-granule index XORed with (row&7).
__device__ __forceinline__ int swz(int row, int colByte, int strideB) {
  return row * strideB + ((((colByte >> 4) ^ (row & 7)) << 4) | (colByte & 15));
}

// lgkm-only barrier: orders LDS producer->consumer, leaves global loads in
// flight (no vmcnt drain). Correctness proven in r5 (passed).
__device__ __forceinline__ void barrier_nd() {
  asm volatile("s_waitcnt lgkmcnt(0)" ::: "memory");
  __builtin_amdgcn_s_barrier();
  asm volatile("" ::: "memory");
}

union CvtU { bf16x2 h; unsigned int u; };
union PaU { unsigned int u[4]; bf16x8 v; };

// ws: bf16 weights [0,147456) elems (294912 B), then bias f32 [6][64][64] (98304 B)
__global__ void prep(const float* __restrict__ qw, const float* __restrict__ kvw,
                     const float* __restrict__ pw, const float* __restrict__ table,
                     bf16_t* __restrict__ wsb, float* __restrict__ biasws) {
  int bid = blockIdx.x;
  if (bid < 144) {
    int i = bid * 256 + threadIdx.x;
#pragma unroll
    for (int j = 0; j < 4; ++j) {
      int e = i * 4 + j;
      float v;
      if (e < 36864) v = qw[e];
      else if (e < 110592) v = kvw[e - 36864];
      else v = pw[e - 110592];
      wsb[e] = (bf16_t)v;
    }
  } else {
    int e = (bid - 144) * 256 + threadIdx.x;  // [0, 24576)
    int h = e >> 12, rc = e & 4095, r = rc >> 6, c = rc & 63;
    int rel = ((r >> 3) - (c >> 3) + 7) * 15 + ((r & 7) - (c & 7) + 7);
    biasws[e] = table[rel * 6 + h];
  }
}

template <bool WS>
__device__ __forceinline__ bf16x8 ldw(const bf16_t* __restrict__ wb,
                                      const float* __restrict__ wf, int off) {
  if constexpr (WS) {
    return *(const bf16x8*)(wb + off);
  } else {
    const float4* p = (const float4*)(wf + off);
    float4 a = p[0], c = p[1];
    bf16x8 r;
    r[0] = (bf16_t)a.x; r[1] = (bf16_t)a.y; r[2] = (bf16_t)a.z; r[3] = (bf16_t)a.w;
    r[4] = (bf16_t)c.x; r[5] = (bf16_t)c.y; r[6] = (bf16_t)c.z; r[7] = (bf16_t)c.w;
    return r;
  }
}

// One block = one window. 512 threads = 8 waves. LDS = 72 KB -> 2 blocks/CU.
//   R0 @     0 : x2 staged -> Q           (stride 384, swizzled)
//   R1 @ 24576 : K -> att-out (per-head)  (stride 384, swizzled)
//   R2 @ 49152 : V^T [192][64]            (stride 128, swizzled)
// Round-6 change: within every phase, ALL independent global loads are issued
// as one batch into registers before the MFMA burst (L2 latency exposed once
// per phase instead of once per kk step). No live range crosses a barrier.
template <bool WS>
__global__ __attribute__((amdgpu_flat_work_group_size(512, 512),
                          amdgpu_waves_per_eu(4, 4)))
void wca_main(
    const float* __restrict__ x1, const float* __restrict__ x2,
    const float* __restrict__ mask,
    const float* __restrict__ qw_f, const float* __restrict__ qb,
    const float* __restrict__ kvw_f, const float* __restrict__ kvb,
    const float* __restrict__ pw_f, const float* __restrict__ pb,
    const float* __restrict__ table,
    const bf16_t* __restrict__ wsb, const float* __restrict__ biasws,
    float* __restrict__ out) {
  extern __shared__ char smem[];
  char* R0 = smem;
  char* R1 = smem + 24576;
  char* R2 = smem + 49152;

  const int t = threadIdx.x;
  const int w = t >> 6, l = t & 63, lo = l & 15, hi = l >> 4;
  const int b = blockIdx.x;
  const int rtB = w & 3, cgB = w >> 2;

  const bf16_t* q_wb = wsb;
  const bf16_t* kv_wb = wsb + 36864;
  const bf16_t* p_wb = wsb + 110592;

  // ---------- stage x2 -> R0: batch all 6 loads, then convert+write ----------
  {
    const float4* s2 = (const float4*)(x2 + (size_t)b * 12288);
    float4 ld[6];
#pragma unroll
    for (int it = 0; it < 3; ++it) {
      int idx = it * 512 + t;
      ld[2 * it] = s2[2 * idx];
      ld[2 * it + 1] = s2[2 * idx + 1];
    }
#pragma unroll
    for (int it = 0; it < 3; ++it) {
      int idx = it * 512 + t;
      int n = idx / 24, g = idx - n * 24;
      float4 a = ld[2 * it], c = ld[2 * it + 1];
      bf16x8 v;
      v[0] = (bf16_t)a.x; v[1] = (bf16_t)a.y; v[2] = (bf16_t)a.z; v[3] = (bf16_t)a.w;
      v[4] = (bf16_t)c.x; v[5] = (bf16_t)c.y; v[6] = (bf16_t)c.z; v[7] = (bf16_t)c.w;
      *(bf16x8*)(R0 + swz(n, g * 16, 384)) = v;
    }
  }
  barrier_nd();

  // ---------- phase A: KV proj. Preload ALL 18 weight frags, 2 row-halves ----------
  // wave w: K cols w*48.. (w<4) or V cols (w-4)*48.. (w>=4)
  {
    bf16x8 wA[6][3];
#pragma unroll
    for (int kk = 0; kk < 6; ++kk)
#pragma unroll
      for (int ct = 0; ct < 3; ++ct) {
        int row = w * 48 + ct * 16 + lo;
        wA[kk][ct] = ldw<WS>(kv_wb, kvw_f, row * 192 + kk * 32 + hi * 8);
      }
#pragma unroll
    for (int h2 = 0; h2 < 2; ++h2) {
      f32x4 acc[2][3];
#pragma unroll
      for (int rt2 = 0; rt2 < 2; ++rt2)
#pragma unroll
        for (int ct = 0; ct < 3; ++ct) { f32x4 z = {0.f, 0.f, 0.f, 0.f}; acc[rt2][ct] = z; }
#pragma unroll
      for (int kk = 0; kk < 6; ++kk) {
        bf16x8 a0 = *(const bf16x8*)(R0 + swz(h2 * 32 + lo, (kk * 4 + hi) * 16, 384));
        bf16x8 a1 = *(const bf16x8*)(R0 + swz(h2 * 32 + 16 + lo, (kk * 4 + hi) * 16, 384));
#pragma unroll
        for (int ct = 0; ct < 3; ++ct) {
          acc[0][ct] = mfma16(a0, wA[kk][ct], acc[0][ct]);
          acc[1][ct] = mfma16(a1, wA[kk][ct], acc[1][ct]);
        }
      }
      if (w < 4) {
#pragma unroll
        for (int ct = 0; ct < 3; ++ct) {
          int och = w * 48 + ct * 16 + lo;
          float bv = kvb[och];
#pragma unroll
          for (int rt2 = 0; rt2 < 2; ++rt2)
#pragma unroll
            for (int i = 0; i < 4; ++i)
              *(bf16_t*)(R1 + swz(h2 * 32 + rt2 * 16 + hi * 4 + i, och * 2, 384)) =
                  (bf16_t)(acc[rt2][ct][i] + bv);
        }
      } else {
#pragma unroll
        for (int ct = 0; ct < 3; ++ct) {
          int och = (w - 4) * 48 + ct * 16 + lo;
          float bv = kvb[192 + och];
#pragma unroll
          for (int rt2 = 0; rt2 < 2; ++rt2) {
            int n0 = h2 * 32 + rt2 * 16 + hi * 4;
            bf16x4 pk;
#pragma unroll
            for (int i = 0; i < 4; ++i) pk[i] = (bf16_t)(acc[rt2][ct][i] + bv);
            *(bf16x4*)(R2 + swz(och, n0 * 2, 128)) = pk;
          }
        }
      }
    }
  }
  barrier_nd();  // x2 reads done; K, V^T ready

  // ---------- phase B: Q proj from global x1, kk-halves with batched loads ----------
  {
    const float4* x1p = (const float4*)(x1 + (size_t)b * 12288 + (rtB * 16 + lo) * 192);
    f32x4 acc[6];
#pragma unroll
    for (int ct = 0; ct < 6; ++ct) { f32x4 z = {0.f, 0.f, 0.f, 0.f}; acc[ct] = z; }
#pragma unroll
    for (int kh = 0; kh < 2; ++kh) {
      float4 xa[3], xb[3];
#pragma unroll
      for (int kk2 = 0; kk2 < 3; ++kk2) {
        xa[kk2] = x1p[(kh * 3 + kk2) * 8 + hi * 2];
        xb[kk2] = x1p[(kh * 3 + kk2) * 8 + hi * 2 + 1];
      }
      bf16x8 wB[3][6];
#pragma unroll
      for (int kk2 = 0; kk2 < 3; ++kk2)
#pragma unroll
        for (int ct = 0; ct < 6; ++ct) {
          int col = cgB * 96 + ct * 16 + lo;
          wB[kk2][ct] = ldw<WS>(q_wb, qw_f, col * 192 + (kh * 3 + kk2) * 32 + hi * 8);
        }
#pragma unroll
      for (int kk2 = 0; kk2 < 3; ++kk2) {
        bf16x8 a;
        a[0] = (bf16_t)xa[kk2].x; a[1] = (bf16_t)xa[kk2].y;
        a[2] = (bf16_t)xa[kk2].z; a[3] = (bf16_t)xa[kk2].w;
        a[4] = (bf16_t)xb[kk2].x; a[5] = (bf16_t)xb[kk2].y;
        a[6] = (bf16_t)xb[kk2].z; a[7] = (bf16_t)xb[kk2].w;
#pragma unroll
        for (int ct = 0; ct < 6; ++ct) acc[ct] = mfma16(a, wB[kk2][ct], acc[ct]);
      }
    }
#pragma unroll
    for (int ct = 0; ct < 6; ++ct) {
      int col = cgB * 96 + ct * 16 + lo;
      float bv = qb[col];
#pragma unroll
      for (int i = 0; i < 4; ++i)
        *(bf16_t*)(R0 + swz(rtB * 16 + hi * 4 + i, col * 2, 384)) =
            (bf16_t)((acc[ct][i] + bv) * SCALE);
    }
  }
  barrier_nd();  // Q ready

  // ---------- attention: wave = (rowtile w>>1, head-half w&1), swapped QK^T ----------
  {
    const int rt3 = w >> 1, hh = w & 1, rbase = rt3 * 16;
    const int r = rbase + lo;
    const float* maskp = mask + (size_t)(b & 1023) * 4096 + r * 64;
    f32x4 mk[4];
    int relidx[4][4];
#pragma unroll
    for (int ct = 0; ct < 4; ++ct) {
      mk[ct] = *(const f32x4*)(maskp + ct * 16 + hi * 4);
      if (!WS) {
#pragma unroll
        for (int i = 0; i < 4; ++i) {
          int c = ct * 16 + hi * 4 + i;
          relidx[ct][i] = (((r >> 3) - (c >> 3) + 7) * 15 + ((r & 7) - (c & 7) + 7)) * 6;
        }
      }
    }
#pragma unroll
    for (int hq = 0; hq < 3; ++hq) {
      const int h = hh * 3 + hq;
      // batch: bias (global) first, then Q + K frags (LDS), then MFMA burst
      f32x4 cb[4];
#pragma unroll
      for (int ct = 0; ct < 4; ++ct) {
        if (WS) {
          cb[ct] = *(const f32x4*)(biasws + h * 4096 + r * 64 + ct * 16 + hi * 4);
        } else {
#pragma unroll
          for (int i = 0; i < 4; ++i) cb[ct][i] = table[relidx[ct][i] + h];
        }
        cb[ct] += mk[ct];
      }
      bf16x8 qa = *(const bf16x8*)(R0 + swz(r, h * 64 + hi * 16, 384));
      bf16x8 ka[4];
#pragma unroll
      for (int ct = 0; ct < 4; ++ct)
        ka[ct] = *(const bf16x8*)(R1 + swz(ct * 16 + lo, h * 64 + hi * 16, 384));
      f32x4 s[4];
#pragma unroll
      for (int ct = 0; ct < 4; ++ct)
        s[ct] = mfma16(ka[ct], qa, cb[ct]);  // S^T: lane holds S[r][ct*16+hi*4+i]
      float mx = -1e30f;
#pragma unroll
      for (int ct = 0; ct < 4; ++ct)
#pragma unroll
        for (int i = 0; i < 4; ++i) mx = fmaxf(mx, s[ct][i]);
      mx = fmaxf(mx, __shfl_xor(mx, 16));
      mx = fmaxf(mx, __shfl_xor(mx, 32));
      float sum = 0.f;
#pragma unroll
      for (int ct = 0; ct < 4; ++ct)
#pragma unroll
        for (int i = 0; i < 4; ++i) {
          float p = __expf(s[ct][i] - mx);
          s[ct][i] = p;
          sum += p;
        }
      sum += __shfl_xor(sum, 16);
      sum += __shfl_xor(sum, 32);
      float rinv = 1.0f / sum;
      unsigned int word[4][2];
#pragma unroll
      for (int ct = 0; ct < 4; ++ct)
#pragma unroll
        for (int i2 = 0; i2 < 2; ++i2) {
          CvtU cu;
          cu.h[0] = (bf16_t)(s[ct][2 * i2] * rinv);
          cu.h[1] = (bf16_t)(s[ct][2 * i2 + 1] * rinv);
          word[ct][i2] = cu.u;
        }
      // PV: build A-frag via shfl word-pulls; batch V reads, then MFMA
      f32x4 o0 = {0.f, 0.f, 0.f, 0.f}, o1 = {0.f, 0.f, 0.f, 0.f};
      bf16x8 v00 = *(const bf16x8*)(R2 + swz(h * 32 + lo, 0 * 64 + hi * 16, 128));
      bf16x8 v01 = *(const bf16x8*)(R2 + swz(h * 32 + 16 + lo, 0 * 64 + hi * 16, 128));
      bf16x8 v10 = *(const bf16x8*)(R2 + swz(h * 32 + lo, 1 * 64 + hi * 16, 128));
      bf16x8 v11 = *(const bf16x8*)(R2 + swz(h * 32 + 16 + lo, 1 * 64 + hi * 16, 128));
#pragma unroll
      for (int k2 = 0; k2 < 2; ++k2) {
        PaU pa;
#pragma unroll
        for (int j2 = 0; j2 < 4; ++j2) {
          int src = lo + ((hi & 1) << 5) + ((j2 >> 1) << 4);
          unsigned int wa = (unsigned int)__shfl((int)word[2 * k2][j2 & 1], src);
          unsigned int wb = (unsigned int)__shfl((int)word[2 * k2 + 1][j2 & 1], src);
          pa.u[j2] = (hi & 2) ? wb : wa;
        }
        o0 = mfma16(pa.v, k2 ? v10 : v00, o0);
        o1 = mfma16(pa.v, k2 ? v11 : v01, o1);
      }
      barrier_nd();  // all QK reads of head hq's K cols complete
#pragma unroll
      for (int i = 0; i < 4; ++i) {
        int rr = rbase + hi * 4 + i;
        *(bf16_t*)(R1 + swz(rr, h * 64 + lo * 2, 384)) = (bf16_t)o0[i];
        *(bf16_t*)(R1 + swz(rr, h * 64 + 32 + lo * 2, 384)) = (bf16_t)o1[i];
      }
    }
  }
  barrier_nd();  // att-out fully in R1

  // ---------- out proj: kk-halves with batched weight loads ----------
  {
    f32x4 acc[6];
#pragma unroll
    for (int ct = 0; ct < 6; ++ct) { f32x4 z = {0.f, 0.f, 0.f, 0.f}; acc[ct] = z; }
#pragma unroll
    for (int kh = 0; kh < 2; ++kh) {
      bf16x8 wB[3][6];
#pragma unroll
      for (int kk2 = 0; kk2 < 3; ++kk2)
#pragma unroll
        for (int ct = 0; ct < 6; ++ct) {
          int col = cgB * 96 + ct * 16 + lo;
          wB[kk2][ct] = ldw<WS>(p_wb, pw_f, col * 192 + (kh * 3 + kk2) * 32 + hi * 8);
        }
#pragma unroll
      for (int kk2 = 0; kk2 < 3; ++kk2) {
        bf16x8 a = *(const bf16x8*)(
            R1 + swz(rtB * 16 + lo, ((kh * 3 + kk2) * 4 + hi) * 16, 384));
#pragma unroll
        for (int ct = 0; ct < 6; ++ct) acc[ct] = mfma16(a, wB[kk2][ct], acc[ct]);
      }
    }
    float* outp = out + (size_t)b * 12288;
#pragma unroll
    for (int ct = 0; ct < 6; ++ct) {
      int col = cgB * 96 + ct * 16 + lo;
      float bv = pb[col];
#pragma unroll
      for (int i = 0; i < 4; ++i)
        outp[(rtB * 16 + hi * 4 + i) * 192 + col] = acc[ct][i] + bv;
    }
  }
}

extern "C" void kernel_launch(void* const* d_in, const int* in_sizes, int n_in,
                              void* d_out, int out_size, void* d_ws, size_t ws_size,
                              hipStream_t stream) {
  const float* x1 = (const float*)d_in[0];
  const float* x2 = (const float*)d_in[1];
  const float* mask = (const float*)d_in[2];
  const float* qw = (const float*)d_in[3];
  const float* qb = (const float*)d_in[4];
  const float* kvw = (const float*)d_in[5];
  const float* kvb = (const float*)d_in[6];
  const float* pw = (const float*)d_in[7];
  const float* pb = (const float*)d_in[8];
  const float* table = (const float*)d_in[9];
  float* out = (float*)d_out;
  bf16_t* wsb = (bf16_t*)d_ws;
  float* biasws = (float*)((char*)d_ws + 294912);
  const int LDS_BYTES = 73728;
  if (ws_size >= 393216) {
    prep<<<240, 256, 0, stream>>>(qw, kvw, pw, table, wsb, biasws);
    wca_main<true><<<8192, 512, LDS_BYTES, stream>>>(x1, x2, mask, qw, qb, kvw, kvb,
                                                     pw, pb, table, wsb, biasws, out);
  } else {
    wca_main<false><<<8192, 512, LDS_BYTES, stream>>>(x1, x2, mask, qw, qb, kvw, kvb,
                                                      pw, pb, table, wsb, biasws, out);
  }
}

// Round 7
// 651.909 us; speedup vs baseline: 3.7710x; 1.5264x over previous
//
#include <hip/hip_runtime.h>

typedef __bf16 bf16_t;
typedef __bf16 bf16x8 __attribute__((ext_vector_type(8)));
typedef __bf16 bf16x4 __attribute__((ext_vector_type(4)));
typedef __bf16 bf16x2 __attribute__((ext_vector_type(2)));
typedef float f32x4 __attribute__((ext_vector_type(4)));

#define SCALE 0.17677669529663687f

__device__ __forceinline__ f32x4 mfma16(bf16x8 a, bf16x8 b, f32x4 c) {
  return __builtin_amdgcn_mfma_f32_16x16x32_bf16(a, b, c, 0, 0, 0);
}

// XOR-swizzled LDS byte offset: 16B-granule index XORed with (row&7).
__device__ __forceinline__ int swz(int row, int colByte, int strideB) {
  return row * strideB + ((((colByte >> 4) ^ (row & 7)) << 4) | (colByte & 15));
}

// lgkm-only barrier: orders LDS producer->consumer, leaves global loads in
// flight. Correctness proven r5/r6.
__device__ __forceinline__ void barrier_nd() {
  asm volatile("s_waitcnt lgkmcnt(0)" ::: "memory");
  __builtin_amdgcn_s_barrier();
  asm volatile("" ::: "memory");
}

union CvtU { bf16x2 h; unsigned int u; };
union PaU { unsigned int u[4]; bf16x8 v; };

// ws: bf16 weights only. q_wb [0,36864) PRE-SCALED by SCALE, kv_wb
// [36864,110592), proj_wb [110592,147456). 294912 bytes.
__global__ void prep(const float* __restrict__ qw, const float* __restrict__ kvw,
                     const float* __restrict__ pw, bf16_t* __restrict__ wsb) {
  int i = blockIdx.x * 256 + threadIdx.x;
#pragma unroll
  for (int j = 0; j < 4; ++j) {
    int e = i * 4 + j;
    float v;
    if (e < 36864) v = qw[e] * SCALE;
    else if (e < 110592) v = kvw[e - 36864];
    else v = pw[e - 110592];
    wsb[e] = (bf16_t)v;
  }
}

template <bool WS>
__device__ __forceinline__ bf16x8 ldw(const bf16_t* __restrict__ wb,
                                      const float* __restrict__ wf, int off) {
  if constexpr (WS) {
    return *(const bf16x8*)(wb + off);
  } else {
    const float4* p = (const float4*)(wf + off);
    float4 a = p[0], c = p[1];
    bf16x8 r;
    r[0] = (bf16_t)a.x; r[1] = (bf16_t)a.y; r[2] = (bf16_t)a.z; r[3] = (bf16_t)a.w;
    r[4] = (bf16_t)c.x; r[5] = (bf16_t)c.y; r[6] = (bf16_t)c.z; r[7] = (bf16_t)c.w;
    return r;
  }
}

// One block = TWO windows (win0=2b, win1=2b+1). 512 threads = 8 waves.
// LDS = 144 KB -> 1 block/CU:
//   RA @      0 : [128][384B] x2 staged -> Q -> att-out (rows wv*64+n)
//   RK @  49152 : [128][384B] K (both windows)
//   RV @  98304 : [2][192][128B] V^T per window
// Barriers: stage->A, A->B, B->attn, attn->out = 4 per 2 windows.
// att-out overwrites Q in RA with NO barrier: each wave reads Q only at
// (its rows) x (its head-half cols) strictly before writing att-out to the
// same (rows x cols); other waves touch disjoint rows (wv,rt32) or disjoint
// cols (hh). No accumulator or load batch crosses a barrier.
template <bool WS>
__global__ __launch_bounds__(512, 2) void wca_main(
    const float* __restrict__ x1, const float* __restrict__ x2,
    const float* __restrict__ mask,
    const float* __restrict__ qw_f, const float* __restrict__ qb,
    const float* __restrict__ kvw_f, const float* __restrict__ kvb,
    const float* __restrict__ pw_f, const float* __restrict__ pb,
    const float* __restrict__ table,
    const bf16_t* __restrict__ wsb,
    float* __restrict__ out) {
  extern __shared__ char smem[];
  char* RA = smem;
  char* RK = smem + 49152;
  char* RV = smem + 98304;

  const int t = threadIdx.x;
  const int w = t >> 6, l = t & 63, lo = l & 15, hi = l >> 4;
  const int win0 = 2 * blockIdx.x;

  const bf16_t* q_wb = wsb;
  const bf16_t* kv_wb = wsb + 36864;
  const bf16_t* p_wb = wsb + 110592;

  // ---------- stage x2 (both windows) -> RA ----------
  {
    const float4* s2a = (const float4*)(x2 + (size_t)win0 * 12288);
    const float4* s2b = (const float4*)(x2 + (size_t)(win0 + 1) * 12288);
    float4 ld[12];
#pragma unroll
    for (int it = 0; it < 3; ++it) {
      int idx = it * 512 + t;
      ld[4 * it + 0] = s2a[2 * idx]; ld[4 * it + 1] = s2a[2 * idx + 1];
      ld[4 * it + 2] = s2b[2 * idx]; ld[4 * it + 3] = s2b[2 * idx + 1];
    }
#pragma unroll
    for (int it = 0; it < 3; ++it) {
      int idx = it * 512 + t;
      int n = idx / 24, g = idx - n * 24;
      bf16x8 v;
      float4 a = ld[4 * it + 0], c = ld[4 * it + 1];
      v[0] = (bf16_t)a.x; v[1] = (bf16_t)a.y; v[2] = (bf16_t)a.z; v[3] = (bf16_t)a.w;
      v[4] = (bf16_t)c.x; v[5] = (bf16_t)c.y; v[6] = (bf16_t)c.z; v[7] = (bf16_t)c.w;
      *(bf16x8*)(RA + swz(n, g * 16, 384)) = v;
      a = ld[4 * it + 2]; c = ld[4 * it + 3];
      v[0] = (bf16_t)a.x; v[1] = (bf16_t)a.y; v[2] = (bf16_t)a.z; v[3] = (bf16_t)a.w;
      v[4] = (bf16_t)c.x; v[5] = (bf16_t)c.y; v[6] = (bf16_t)c.z; v[7] = (bf16_t)c.w;
      *(bf16x8*)(RA + swz(64 + n, g * 16, 384)) = v;
    }
  }
  barrier_nd();

  // ---------- phase A: KV proj, weights preloaded once, 2 windows ----------
  // wave w: K cols w*48.. (w<4) | V cols (w-4)*48.. (w>=4). Full dedup.
  {
    bf16x8 wA[6][3];
#pragma unroll
    for (int kk = 0; kk < 6; ++kk)
#pragma unroll
      for (int ct = 0; ct < 3; ++ct) {
        int row = w * 48 + ct * 16 + lo;
        wA[kk][ct] = ldw<WS>(kv_wb, kvw_f, row * 192 + kk * 32 + hi * 8);
      }
    for (int wv = 0; wv < 2; ++wv) {
      f32x4 acc[4][3];
#pragma unroll
      for (int rt = 0; rt < 4; ++rt)
#pragma unroll
        for (int ct = 0; ct < 3; ++ct) { f32x4 z = {0.f, 0.f, 0.f, 0.f}; acc[rt][ct] = z; }
#pragma unroll
      for (int kk = 0; kk < 6; ++kk) {
        bf16x8 a[4];
#pragma unroll
        for (int rt = 0; rt < 4; ++rt)
          a[rt] = *(const bf16x8*)(RA + swz(wv * 64 + rt * 16 + lo, (kk * 4 + hi) * 16, 384));
#pragma unroll
        for (int rt = 0; rt < 4; ++rt)
#pragma unroll
          for (int ct = 0; ct < 3; ++ct)
            acc[rt][ct] = mfma16(a[rt], wA[kk][ct], acc[rt][ct]);
      }
      if (w < 4) {
#pragma unroll
        for (int ct = 0; ct < 3; ++ct) {
          int och = w * 48 + ct * 16 + lo;
          float bv = kvb[och];
#pragma unroll
          for (int rt = 0; rt < 4; ++rt)
#pragma unroll
            for (int i = 0; i < 4; ++i)
              *(bf16_t*)(RK + swz(wv * 64 + rt * 16 + hi * 4 + i, och * 2, 384)) =
                  (bf16_t)(acc[rt][ct][i] + bv);
        }
      } else {
#pragma unroll
        for (int ct = 0; ct < 3; ++ct) {
          int och = (w - 4) * 48 + ct * 16 + lo;
          float bv = kvb[192 + och];
#pragma unroll
          for (int rt = 0; rt < 4; ++rt) {
            int n0 = rt * 16 + hi * 4;
            bf16x4 pk;
#pragma unroll
            for (int i = 0; i < 4; ++i) pk[i] = (bf16_t)(acc[rt][ct][i] + bv);
            *(bf16x4*)(RV + wv * 24576 + swz(och, n0 * 2, 128)) = pk;
          }
        }
      }
    }
  }
  barrier_nd();  // x2 reads done; K, V^T ready

  // ---------- phase B: Q proj from global x1 -> RA ----------
  // wave: wv = w>>2, rt2 = (w>>1)&1 (32 rows), cg = w&1 (96 cols)
  {
    const int wv = w >> 2, rt2 = (w >> 1) & 1, cg = w & 1;
    const float* x1w = x1 + (size_t)(win0 + wv) * 12288;
    f32x4 acc[2][6];
#pragma unroll
    for (int rt = 0; rt < 2; ++rt)
#pragma unroll
      for (int ct = 0; ct < 6; ++ct) { f32x4 z = {0.f, 0.f, 0.f, 0.f}; acc[rt][ct] = z; }
#pragma unroll
    for (int kh = 0; kh < 2; ++kh) {
      float4 xf[2][3][2];
#pragma unroll
      for (int rt = 0; rt < 2; ++rt) {
        const float4* p = (const float4*)(x1w + (rt2 * 32 + rt * 16 + lo) * 192);
#pragma unroll
        for (int k2 = 0; k2 < 3; ++k2) {
          xf[rt][k2][0] = p[(kh * 3 + k2) * 8 + hi * 2];
          xf[rt][k2][1] = p[(kh * 3 + k2) * 8 + hi * 2 + 1];
        }
      }
      bf16x8 wB[3][6];
#pragma unroll
      for (int k2 = 0; k2 < 3; ++k2)
#pragma unroll
        for (int ct = 0; ct < 6; ++ct) {
          int col = cg * 96 + ct * 16 + lo;
          wB[k2][ct] = ldw<WS>(q_wb, qw_f, col * 192 + (kh * 3 + k2) * 32 + hi * 8);
        }
#pragma unroll
      for (int k2 = 0; k2 < 3; ++k2)
#pragma unroll
        for (int rt = 0; rt < 2; ++rt) {
          bf16x8 a;
          float4 xa = xf[rt][k2][0], xb = xf[rt][k2][1];
          a[0] = (bf16_t)xa.x; a[1] = (bf16_t)xa.y; a[2] = (bf16_t)xa.z; a[3] = (bf16_t)xa.w;
          a[4] = (bf16_t)xb.x; a[5] = (bf16_t)xb.y; a[6] = (bf16_t)xb.z; a[7] = (bf16_t)xb.w;
#pragma unroll
          for (int ct = 0; ct < 6; ++ct) acc[rt][ct] = mfma16(a, wB[k2][ct], acc[rt][ct]);
        }
    }
#pragma unroll
    for (int ct = 0; ct < 6; ++ct) {
      int col = cg * 96 + ct * 16 + lo;
      float qbs = qb[col] * SCALE;
#pragma unroll
      for (int rt = 0; rt < 2; ++rt)
#pragma unroll
        for (int i = 0; i < 4; ++i) {
          int row = wv * 64 + rt2 * 32 + rt * 16 + hi * 4 + i;
          float val = WS ? (acc[rt][ct][i] + qbs) : (acc[rt][ct][i] + qb[col]) * SCALE;
          *(bf16_t*)(RA + swz(row, col * 2, 384)) = (bf16_t)val;
        }
    }
  }
  barrier_nd();  // Q ready

  // ---------- attention: wave = (wv = w>>2, rt32 = (w>>1)&1, hh = w&1) ----------
  // Per wave: 32 q-rows (2 sub-tiles of 16) x 3 heads. Bias via 5.4 KB table
  // gather (L1-resident). att-out overwrites Q in RA, no barriers (see top).
  {
    const int wv = w >> 2, rt32 = (w >> 1) & 1, hh = w & 1;
    const int win = win0 + wv;
    const float* maskb = mask + (size_t)(win & 1023) * 4096;
    f32x4 mk[2][4];
    int ridx[2][4][4];
#pragma unroll
    for (int rts = 0; rts < 2; ++rts) {
      int r = rt32 * 32 + rts * 16 + lo;
#pragma unroll
      for (int ct = 0; ct < 4; ++ct) {
        mk[rts][ct] = *(const f32x4*)(maskb + r * 64 + ct * 16 + hi * 4);
#pragma unroll
        for (int i = 0; i < 4; ++i) {
          int c = ct * 16 + hi * 4 + i;
          ridx[rts][ct][i] = (((r >> 3) - (c >> 3) + 7) * 15 + ((r & 7) - (c & 7) + 7)) * 6;
        }
      }
    }
#pragma unroll
    for (int hq = 0; hq < 3; ++hq) {
      const int h = hh * 3 + hq;
#pragma unroll
      for (int rts = 0; rts < 2; ++rts) {
        const int rbase = rt32 * 32 + rts * 16;
        const int r = rbase + lo;
        bf16x8 qa = *(const bf16x8*)(RA + swz(wv * 64 + r, h * 64 + hi * 16, 384));
        f32x4 s[4];
#pragma unroll
        for (int ct = 0; ct < 4; ++ct) {
          f32x4 ci;
#pragma unroll
          for (int i = 0; i < 4; ++i) ci[i] = table[ridx[rts][ct][i] + h];
          ci += mk[rts][ct];
          bf16x8 ka = *(const bf16x8*)(RK + swz(wv * 64 + ct * 16 + lo, h * 64 + hi * 16, 384));
          s[ct] = mfma16(ka, qa, ci);  // S^T: lane holds S[r][ct*16+hi*4+i]
        }
        float mx = -1e30f;
#pragma unroll
        for (int ct = 0; ct < 4; ++ct)
#pragma unroll
          for (int i = 0; i < 4; ++i) mx = fmaxf(mx, s[ct][i]);
        mx = fmaxf(mx, __shfl_xor(mx, 16));
        mx = fmaxf(mx, __shfl_xor(mx, 32));
        float sum = 0.f;
#pragma unroll
        for (int ct = 0; ct < 4; ++ct)
#pragma unroll
          for (int i = 0; i < 4; ++i) {
            float p = __expf(s[ct][i] - mx);
            s[ct][i] = p;
            sum += p;
          }
        sum += __shfl_xor(sum, 16);
        sum += __shfl_xor(sum, 32);
        float rinv = 1.0f / sum;
        unsigned int word[4][2];
#pragma unroll
        for (int ct = 0; ct < 4; ++ct)
#pragma unroll
          for (int i2 = 0; i2 < 2; ++i2) {
            CvtU cu;
            cu.h[0] = (bf16_t)(s[ct][2 * i2] * rinv);
            cu.h[1] = (bf16_t)(s[ct][2 * i2 + 1] * rinv);
            word[ct][i2] = cu.u;
          }
        // PV: build A-frag P[rbase+lo][k-run] via shfl word-pulls
        f32x4 o0 = {0.f, 0.f, 0.f, 0.f}, o1 = {0.f, 0.f, 0.f, 0.f};
#pragma unroll
        for (int k2 = 0; k2 < 2; ++k2) {
          PaU pa;
#pragma unroll
          for (int j2 = 0; j2 < 4; ++j2) {
            int src = lo + ((hi & 1) << 5) + ((j2 >> 1) << 4);
            unsigned int wa = (unsigned int)__shfl((int)word[2 * k2][j2 & 1], src);
            unsigned int wb = (unsigned int)__shfl((int)word[2 * k2 + 1][j2 & 1], src);
            pa.u[j2] = (hi & 2) ? wb : wa;
          }
          bf16x8 v0 = *(const bf16x8*)(RV + wv * 24576 + swz(h * 32 + lo, k2 * 64 + hi * 16, 128));
          bf16x8 v1 = *(const bf16x8*)(RV + wv * 24576 + swz(h * 32 + 16 + lo, k2 * 64 + hi * 16, 128));
          o0 = mfma16(pa.v, v0, o0);
          o1 = mfma16(pa.v, v1, o1);
        }
#pragma unroll
        for (int i = 0; i < 4; ++i) {
          int rr = wv * 64 + rbase + hi * 4 + i;
          *(bf16_t*)(RA + swz(rr, h * 64 + lo * 2, 384)) = (bf16_t)o0[i];
          *(bf16_t*)(RA + swz(rr, h * 64 + 32 + lo * 2, 384)) = (bf16_t)o1[i];
        }
      }
    }
  }
  barrier_nd();  // att-out fully in RA

  // ---------- out proj: wave = (wv = w>>2, cgo = w&3 -> 48 cols) ----------
  {
    const int wv = w >> 2, cgo = w & 3;
    bf16x8 wO[6][3];
#pragma unroll
    for (int kk = 0; kk < 6; ++kk)
#pragma unroll
      for (int ct = 0; ct < 3; ++ct) {
        int col = cgo * 48 + ct * 16 + lo;
        wO[kk][ct] = ldw<WS>(p_wb, pw_f, col * 192 + kk * 32 + hi * 8);
      }
    f32x4 acc[4][3];
#pragma unroll
    for (int rt = 0; rt < 4; ++rt)
#pragma unroll
      for (int ct = 0; ct < 3; ++ct) { f32x4 z = {0.f, 0.f, 0.f, 0.f}; acc[rt][ct] = z; }
#pragma unroll
    for (int kk = 0; kk < 6; ++kk) {
      bf16x8 a[4];
#pragma unroll
      for (int rt = 0; rt < 4; ++rt)
        a[rt] = *(const bf16x8*)(RA + swz(wv * 64 + rt * 16 + lo, (kk * 4 + hi) * 16, 384));
#pragma unroll
      for (int rt = 0; rt < 4; ++rt)
#pragma unroll
        for (int ct = 0; ct < 3; ++ct)
          acc[rt][ct] = mfma16(a[rt], wO[kk][ct], acc[rt][ct]);
    }
    float* outp = out + (size_t)(win0 + wv) * 12288;
#pragma unroll
    for (int ct = 0; ct < 3; ++ct) {
      int col = cgo * 48 + ct * 16 + lo;
      float bv = pb[col];
#pragma unroll
      for (int rt = 0; rt < 4; ++rt)
#pragma unroll
        for (int i = 0; i < 4; ++i)
          outp[(rt * 16 + hi * 4 + i) * 192 + col] = acc[rt][ct][i] + bv;
    }
  }
}

extern "C" void kernel_launch(void* const* d_in, const int* in_sizes, int n_in,
                              void* d_out, int out_size, void* d_ws, size_t ws_size,
                              hipStream_t stream) {
  const float* x1 = (const float*)d_in[0];
  const float* x2 = (const float*)d_in[1];
  const float* mask = (const float*)d_in[2];
  const float* qw = (const float*)d_in[3];
  const float* qb = (const float*)d_in[4];
  const float* kvw = (const float*)d_in[5];
  const float* kvb = (const float*)d_in[6];
  const float* pw = (const float*)d_in[7];
  const float* pb = (const float*)d_in[8];
  const float* table = (const float*)d_in[9];
  float* out = (float*)d_out;
  bf16_t* wsb = (bf16_t*)d_ws;
  const int LDS_BYTES = 147456;
  if (ws_size >= 294912) {
    prep<<<144, 256, 0, stream>>>(qw, kvw, pw, wsb);
    wca_main<true><<<4096, 512, LDS_BYTES, stream>>>(x1, x2, mask, qw, qb, kvw, kvb,
                                                     pw, pb, table, wsb, out);
  } else {
    wca_main<false><<<4096, 512, LDS_BYTES, stream>>>(x1, x2, mask, qw, qb, kvw, kvb,
                                                      pw, pb, table, wsb, out);
  }
}